// Round 1
// baseline (196.317 us; speedup 1.0000x reference)
//
#include <hip/hip_runtime.h>
#include <cstdint>
#include <cmath>

#define DD 2048
#define NROW 4096
#define BHALF 2048

typedef __attribute__((ext_vector_type(8))) __bf16 bf16x8;
typedef __attribute__((ext_vector_type(4))) float f32x4;

typedef __attribute__((address_space(1))) const void* as1cv;
typedef __attribute__((address_space(3))) void* as3v;

__device__ __forceinline__ void gload_lds16(const void* g, void* l) {
  __builtin_amdgcn_global_load_lds((as1cv)g, (as3v)l, 16, 0, 0);
}

__device__ __forceinline__ float fixv(float x) {
  if (isnan(x)) return 0.0f;
  if (isinf(x)) return x > 0.0f ? 10000.0f : -10000.0f;
  return x;
}

// ---- workspace layout (bytes) ----
constexpr size_t TB_OFF     = 0;                              // bf16 total [4096][2048]
constexpr size_t SQ_OFF     = (size_t)NROW * DD * 2;          // 16,777,216  f32[4096]
constexpr size_t CS_SRC_OFF = SQ_OFF + NROW * 4;              // f32[2048]
constexpr size_t CS_TGT_OFF = CS_SRC_OFF + DD * 4;            // f32[2048]
constexpr size_t ACC_OFF    = CS_TGT_OFF + DD * 4;            // f64[4]  (8-aligned)
constexpr size_t SCAL_OFF   = ACC_OFF + 4 * 8;                // f32 bw, f32 lin

// Pass 1: nan_to_num, row sum-of-squares (fp32), bf16 conversion of total.
__global__ __launch_bounds__(256) void k_prep(const float* __restrict__ src,
                                              const float* __restrict__ tgt,
                                              __bf16* __restrict__ Tb,
                                              float* __restrict__ sq) {
  int row = blockIdx.x;
  const float* in = (row < BHALF) ? (src + (size_t)row * DD)
                                  : (tgt + (size_t)(row - BHALF) * DD);
  int t = threadIdx.x;
  const float4* p = (const float4*)in + t * 2;
  float4 v0 = p[0], v1 = p[1];
  float x[8] = {v0.x, v0.y, v0.z, v0.w, v1.x, v1.y, v1.z, v1.w};
  float acc = 0.0f;
  bf16x8 b;
#pragma unroll
  for (int j = 0; j < 8; ++j) {
    float f = fixv(x[j]);
    acc += f * f;
    b[j] = (__bf16)f;
  }
  *(bf16x8*)(Tb + (size_t)row * DD + t * 8) = b;
  for (int o = 32; o; o >>= 1) acc += __shfl_xor(acc, o);
  __shared__ float redbuf[4];
  if ((t & 63) == 0) redbuf[t >> 6] = acc;
  __syncthreads();
  if (t == 0) sq[row] = redbuf[0] + redbuf[1] + redbuf[2] + redbuf[3];
}

// Pass 2: column sums of source rows and target rows (for bw + linear fallback).
__global__ __launch_bounds__(256) void k_colsum(const float* __restrict__ src,
                                                const float* __restrict__ tgt,
                                                float* __restrict__ cs_src,
                                                float* __restrict__ cs_tgt) {
  int c = blockIdx.x * 256 + threadIdx.x;
  int r0 = blockIdx.y * 256;
  const float* in;
  float* outp;
  if (r0 < BHALF) { in = src + (size_t)r0 * DD; outp = cs_src; }
  else            { in = tgt + (size_t)(r0 - BHALF) * DD; outp = cs_tgt; }
  float acc = 0.0f;
  for (int r = 0; r < 256; ++r) acc += fixv(in[(size_t)r * DD + c]);
  atomicAdd(outp + c, acc);
}

// Pass 3: bandwidth bw = max(mean(L2), EPS) analytically; linear-MMD fallback value.
__global__ __launch_bounds__(256) void k_bw(const float* __restrict__ sq,
                                            const float* __restrict__ cs_src,
                                            const float* __restrict__ cs_tgt,
                                            float* __restrict__ scal) {
  int t = threadIdx.x;
  float ssq = 0.0f;
  for (int i = t; i < NROW; i += 256) ssq += sq[i];
  float s2 = 0.0f, dl = 0.0f;
  for (int c = t; c < DD; c += 256) {
    float a = cs_src[c], bb = cs_tgt[c];
    float s = a + bb;
    s2 += s * s;
    float d = (a - bb) * (1.0f / BHALF);
    dl += d * d;
  }
  for (int o = 32; o; o >>= 1) {
    ssq += __shfl_xor(ssq, o);
    s2  += __shfl_xor(s2, o);
    dl  += __shfl_xor(dl, o);
  }
  __shared__ float w0[4], w1[4], w2[4];
  if ((t & 63) == 0) { int w = t >> 6; w0[w] = ssq; w1[w] = s2; w2[w] = dl; }
  __syncthreads();
  if (t == 0) {
    double S = (double)w0[0] + w0[1] + w0[2] + w0[3];
    double Q = (double)w1[0] + w1[1] + w1[2] + w1[3];
    double L = (double)w2[0] + w2[1] + w2[2] + w2[3];
    double meanL2 = 2.0 * S / (double)NROW - 2.0 * Q / ((double)NROW * (double)NROW);
    scal[0] = (float)fmax(meanL2, 1e-6);
    scal[1] = (float)L;
  }
}

// Main: fused Gram-GEMM (bf16 MFMA) + RBF-kernel epilogue + quadrant sums.
// Symmetric: only blocks bi <= bj computed; off-diagonal blocks credited to both (i,j) and (j,i).
__global__ __launch_bounds__(256) void k_mmd(const __bf16* __restrict__ Tb,
                                             const float* __restrict__ sq,
                                             const float* __restrict__ scal,
                                             double* __restrict__ accd) {
  int bi = blockIdx.y, bj = blockIdx.x;
  if (bi > bj) return;  // symmetry: upper triangle only

  __shared__ __attribute__((aligned(16))) __bf16 As[128 * 32];
  __shared__ __attribute__((aligned(16))) __bf16 Bs[128 * 32];
  __shared__ float red[4];

  int tid = threadIdx.x, l = tid & 63, w = tid >> 6;
  int wrow = w >> 1, wcol = w & 1;

  f32x4 acc[4][4];
#pragma unroll
  for (int m = 0; m < 4; ++m)
#pragma unroll
    for (int n = 0; n < 4; ++n) acc[m][n] = (f32x4){0.0f, 0.0f, 0.0f, 0.0f};

  // staging address setup: chunk = w*2+q covers 16 rows x 32 cols (1 KiB)
  const __bf16* gA[2];
  const __bf16* gB[2];
  __bf16* dA[2];
  __bf16* dB[2];
#pragma unroll
  for (int q = 0; q < 2; ++q) {
    int chunk = w * 2 + q;
    int rin = chunk * 16 + (l >> 2);
    int ce = (l & 3) * 8;
    gA[q] = Tb + (size_t)(bi * 128 + rin) * DD + ce;
    gB[q] = Tb + (size_t)(bj * 128 + rin) * DD + ce;
    dA[q] = As + chunk * 512;  // wave-uniform LDS base; HW adds lane*16B
    dB[q] = Bs + chunk * 512;
  }

  for (int kk = 0; kk < DD / 32; ++kk) {
    __syncthreads();
#pragma unroll
    for (int q = 0; q < 2; ++q) {
      gload_lds16(gA[q] + kk * 32, dA[q]);
      gload_lds16(gB[q] + kk * 32, dB[q]);
    }
    __syncthreads();
    bf16x8 aF[4], bF[4];
#pragma unroll
    for (int m = 0; m < 4; ++m)
      aF[m] = *(const bf16x8*)(As + (wrow * 64 + m * 16 + (l & 15)) * 32 + (l >> 4) * 8);
#pragma unroll
    for (int n = 0; n < 4; ++n)
      bF[n] = *(const bf16x8*)(Bs + (wcol * 64 + n * 16 + (l & 15)) * 32 + (l >> 4) * 8);
#pragma unroll
    for (int m = 0; m < 4; ++m)
#pragma unroll
      for (int n = 0; n < 4; ++n)
        acc[m][n] = __builtin_amdgcn_mfma_f32_16x16x32_bf16(aF[m], bF[n], acc[m][n], 0, 0, 0);
  }

  // epilogue: L2 -> 5-kernel RBF sum, per-block reduction
  float bw = scal[0];
  float inv[5];
#pragma unroll
  for (int i = 0; i < 5; ++i) inv[i] = 1.0f / (bw * (float)(1 << i));

  float sum = 0.0f;
  int rbase = bi * 128 + wrow * 64 + ((l >> 4) * 4);
  int cbase = bj * 128 + wcol * 64 + (l & 15);
#pragma unroll
  for (int m = 0; m < 4; ++m) {
    float4 sr = *(const float4*)(sq + rbase + m * 16);
    float sqr[4] = {sr.x, sr.y, sr.z, sr.w};
#pragma unroll
    for (int n = 0; n < 4; ++n) {
      float sc = sq[cbase + n * 16];
#pragma unroll
      for (int r = 0; r < 4; ++r) {
        float L2 = sqr[r] + sc - 2.0f * acc[m][n][r];
        L2 = fmaxf(L2, 0.0f);
#pragma unroll
        for (int i = 0; i < 5; ++i) {
          float s = fminf(L2 * inv[i], 50.0f);
          sum += __expf(-s);
        }
      }
    }
  }
  for (int o = 32; o; o >>= 1) sum += __shfl_xor(sum, o);
  if (l == 0) red[w] = sum;
  __syncthreads();
  if (tid == 0) {
    double tot = (double)red[0] + red[1] + red[2] + red[3];
    int cat = (bi >= 16) * 2 + (bj >= 16);
    atomicAdd(accd + cat, tot);
    if (bi != bj) {
      int catT = (bj >= 16) * 2 + (bi >= 16);
      atomicAdd(accd + catT, tot);
    }
  }
}

__global__ void k_final(const double* __restrict__ accd,
                        const float* __restrict__ scal,
                        float* __restrict__ out) {
  double loss = (accd[0] + accd[3] - accd[1] - accd[2]) * (1.0 / 4194304.0);
  if (!isfinite(loss)) loss = (double)scal[1];
  out[0] = (float)loss;
}

extern "C" void kernel_launch(void* const* d_in, const int* in_sizes, int n_in,
                              void* d_out, int out_size, void* d_ws, size_t ws_size,
                              hipStream_t stream) {
  const float* src = (const float*)d_in[0];
  const float* tgt = (const float*)d_in[1];
  char* ws = (char*)d_ws;
  __bf16* Tb     = (__bf16*)(ws + TB_OFF);
  float*  sq     = (float*)(ws + SQ_OFF);
  float*  cs_src = (float*)(ws + CS_SRC_OFF);
  float*  cs_tgt = (float*)(ws + CS_TGT_OFF);
  double* accd   = (double*)(ws + ACC_OFF);
  float*  scal   = (float*)(ws + SCAL_OFF);

  // zero colsums + category accumulators (ws is NOT re-poisoned between replays)
  hipMemsetAsync(ws + CS_SRC_OFF, 0, (DD * 4) * 2 + 4 * 8, stream);

  k_prep<<<NROW, 256, 0, stream>>>(src, tgt, Tb, sq);
  k_colsum<<<dim3(DD / 256, NROW / 256), 256, 0, stream>>>(src, tgt, cs_src, cs_tgt);
  k_bw<<<1, 256, 0, stream>>>(sq, cs_src, cs_tgt, scal);
  k_mmd<<<dim3(32, 32), 256, 0, stream>>>(Tb, sq, scal, accd);
  k_final<<<1, 1, 0, stream>>>(accd, scal, (float*)d_out);
}

// Round 2
// 144.893 us; speedup vs baseline: 1.3549x; 1.3549x over previous
//
#include <hip/hip_runtime.h>
#include <cstdint>
#include <cmath>

#define DD 2048
#define NROW 4096
#define BHALF 2048
#define NB 32            // 4096 / 128 tiles
#define NTRI 528         // NB*(NB+1)/2

typedef __attribute__((ext_vector_type(8))) __bf16 bf16x8;
typedef __attribute__((ext_vector_type(4))) float f32x4;

typedef __attribute__((address_space(1))) const void* as1cv;
typedef __attribute__((address_space(3))) void* as3v;

__device__ __forceinline__ void gload_lds16(const void* g, void* l) {
  __builtin_amdgcn_global_load_lds((as1cv)g, (as3v)l, 16, 0, 0);
}

__device__ __forceinline__ float fixv(float x) {
  if (isnan(x)) return 0.0f;
  if (isinf(x)) return x > 0.0f ? 10000.0f : -10000.0f;
  return x;
}

// ---- workspace layout (bytes) ----
constexpr size_t TB_OFF     = 0;                              // bf16 total [4096][2048]
constexpr size_t SQ_OFF     = (size_t)NROW * DD * 2;          // f32[4096]
constexpr size_t CS_SRC_OFF = SQ_OFF + NROW * 4;              // f32[2048]
constexpr size_t CS_TGT_OFF = CS_SRC_OFF + DD * 4;            // f32[2048]
constexpr size_t ACC_OFF    = CS_TGT_OFF + DD * 4;            // f64[4]
constexpr size_t SCAL_OFF   = ACC_OFF + 4 * 8;                // f32 bw, f32 lin

// Pass 1 (fused): nan_to_num, bf16 convert, row sum-of-squares, column sums.
__global__ __launch_bounds__(256) void k_prep(const float* __restrict__ src,
                                              const float* __restrict__ tgt,
                                              __bf16* __restrict__ Tb,
                                              float* __restrict__ sq,
                                              float* __restrict__ cs_src,
                                              float* __restrict__ cs_tgt) {
  int b = blockIdx.x;            // 256 blocks, 16 rows each
  int t = threadIdx.x, l = t & 63, w = t >> 6;
  int row0 = b * 16;
  const float* base = (b < 128) ? (src + (size_t)row0 * DD)
                                : (tgt + (size_t)(row0 - BHALF) * DD);
  float* csp = (b < 128) ? cs_src : cs_tgt;
  int c0 = t * 8;
  float cacc[8] = {0, 0, 0, 0, 0, 0, 0, 0};
  __shared__ float rbuf[4][16];
#pragma unroll 4
  for (int r = 0; r < 16; ++r) {
    const float4* p = (const float4*)(base + (size_t)r * DD + c0);
    float4 v0 = p[0], v1 = p[1];
    float x[8] = {v0.x, v0.y, v0.z, v0.w, v1.x, v1.y, v1.z, v1.w};
    bf16x8 bb;
    float a = 0.0f;
#pragma unroll
    for (int j = 0; j < 8; ++j) {
      float f = fixv(x[j]);
      a += f * f;
      cacc[j] += f;
      bb[j] = (__bf16)f;
    }
    *(bf16x8*)(Tb + (size_t)(row0 + r) * DD + c0) = bb;
    for (int o = 32; o; o >>= 1) a += __shfl_xor(a, o);
    if (l == 0) rbuf[w][r] = a;
  }
  __syncthreads();
  if (t < 16) sq[row0 + t] = rbuf[0][t] + rbuf[1][t] + rbuf[2][t] + rbuf[3][t];
#pragma unroll
  for (int j = 0; j < 8; ++j) atomicAdd(&csp[c0 + j], cacc[j]);
}

// Pass 2: bandwidth analytically + linear-MMD fallback.
__global__ __launch_bounds__(1024) void k_bw(const float* __restrict__ sq,
                                             const float* __restrict__ cs_src,
                                             const float* __restrict__ cs_tgt,
                                             float* __restrict__ scal) {
  int t = threadIdx.x, l = t & 63, w = t >> 6;
  float ssq = 0.0f;
#pragma unroll
  for (int i = 0; i < 4; ++i) ssq += sq[t + i * 1024];
  float s2 = 0.0f, dl = 0.0f;
#pragma unroll
  for (int i = 0; i < 2; ++i) {
    int c = t + i * 1024;
    float a = cs_src[c], bb = cs_tgt[c];
    float s = a + bb;
    s2 += s * s;
    float d = (a - bb) * (1.0f / BHALF);
    dl += d * d;
  }
  for (int o = 32; o; o >>= 1) {
    ssq += __shfl_xor(ssq, o);
    s2  += __shfl_xor(s2, o);
    dl  += __shfl_xor(dl, o);
  }
  __shared__ float w0[16], w1[16], w2[16];
  if (l == 0) { w0[w] = ssq; w1[w] = s2; w2[w] = dl; }
  __syncthreads();
  if (t == 0) {
    double S = 0.0, Q = 0.0, L = 0.0;
    for (int i = 0; i < 16; ++i) { S += w0[i]; Q += w1[i]; L += w2[i]; }
    double meanL2 = 2.0 * S / (double)NROW - 2.0 * Q / ((double)NROW * (double)NROW);
    scal[0] = (float)fmax(meanL2, 1e-6);
    scal[1] = (float)L;
  }
}

// Main: fused Gram-GEMM + RBF epilogue. Triangle grid (528 blocks), BK=64,
// 2-phase double-buffered LDS (stage next tile before computing current),
// XOR bank-swizzle via pre-swizzled global source (linear gload_lds dest).
__global__ __launch_bounds__(256, 2) void k_mmd(const __bf16* __restrict__ Tb,
                                                const float* __restrict__ sq,
                                                const float* __restrict__ scal,
                                                double* __restrict__ accd) {
  // XCD-chunked swizzle (528 % 8 == 0 -> bijective), then triangle decode
  int lin = blockIdx.x;
  int t5 = (lin & 7) * (NTRI / 8) + (lin >> 3);
  int bi = (int)((65.0 - sqrt(4225.0 - 8.0 * (double)t5)) * 0.5);
  if (bi > NB - 1) bi = NB - 1;
  while (32 * (bi + 1) - ((bi + 1) * bi) / 2 <= t5) ++bi;
  while (32 * bi - (bi * (bi - 1)) / 2 > t5) --bi;
  int bj = bi + (t5 - (32 * bi - (bi * (bi - 1)) / 2));

  // LDS: [2 buf][2 kk2][128 rows][32 cols] per matrix = 64 KiB total
  __shared__ __attribute__((aligned(16))) __bf16 As[2][8192];
  __shared__ __attribute__((aligned(16))) __bf16 Bs[2][8192];

  int tid = threadIdx.x, l = tid & 63, w = tid >> 6;
  int wrow = w >> 1, wcol = w & 1;
  int arow0 = wrow * 64, brow0 = wcol * 64;
  int l15 = l & 15;
  // swizzled read slot: logical slot (l>>4) XOR f(row), f(row)=(row>>1)&3
  int ps = (((l >> 4) ^ ((l15 >> 1) & 3))) * 8;

  f32x4 acc[4][4];
#pragma unroll
  for (int m = 0; m < 4; ++m)
#pragma unroll
    for (int n = 0; n < 4; ++n) acc[m][n] = (f32x4){0.0f, 0.0f, 0.0f, 0.0f};

  // staging addresses: chunk c14 = q*4+w covers 16 rows x 32 cols (1 KiB)
  // lane l -> row (l>>2), phys slot (l&3); source col pre-swizzled so that
  // LDS linear layout holds logical slot (l&3)^((row>>1)&3) at phys (l&3).
  const __bf16* gA[4];
  const __bf16* gB[4];
  int dchunk[4];
#pragma unroll
  for (int q = 0; q < 4; ++q) {
    int c14 = q * 4 + w;
    int r = (c14 & 7) * 16 + (l >> 2);
    int kk2 = c14 >> 3;
    int colsw = ((l & 3) ^ ((l >> 3) & 3)) * 8;
    gA[q] = Tb + (size_t)(bi * 128 + r) * DD + kk2 * 32 + colsw;
    gB[q] = Tb + (size_t)(bj * 128 + r) * DD + kk2 * 32 + colsw;
    dchunk[q] = c14 * 512;
  }

  auto STAGE = [&](int sel, int kk) {
#pragma unroll
    for (int q = 0; q < 4; ++q) {
      gload_lds16(gA[q] + kk * 64, (void*)&As[sel][dchunk[q]]);
      gload_lds16(gB[q] + kk * 64, (void*)&Bs[sel][dchunk[q]]);
    }
  };

  auto COMPUTE = [&](int sel) {
    bf16x8 aF[2][4], bF[2][4];
#pragma unroll
    for (int kk2 = 0; kk2 < 2; ++kk2)
#pragma unroll
      for (int m = 0; m < 4; ++m) {
        aF[kk2][m] = *(const bf16x8*)(&As[sel][0] + kk2 * 4096 + (arow0 + m * 16 + l15) * 32 + ps);
        bF[kk2][m] = *(const bf16x8*)(&Bs[sel][0] + kk2 * 4096 + (brow0 + m * 16 + l15) * 32 + ps);
      }
#pragma unroll
    for (int kk2 = 0; kk2 < 2; ++kk2)
#pragma unroll
      for (int m = 0; m < 4; ++m)
#pragma unroll
        for (int n = 0; n < 4; ++n)
          acc[m][n] = __builtin_amdgcn_mfma_f32_16x16x32_bf16(aF[kk2][m], bF[kk2][n], acc[m][n], 0, 0, 0);
  };

  // 2-phase pipeline over 32 K-steps (BK=64): one barrier per step.
  STAGE(0, 0);
  __syncthreads();
#pragma unroll 1
  for (int kk = 0; kk < 30; kk += 2) {
    STAGE(1, kk + 1);
    COMPUTE(0);
    __syncthreads();
    STAGE(0, kk + 2);
    COMPUTE(1);
    __syncthreads();
  }
  STAGE(1, 31);
  COMPUTE(0);
  __syncthreads();
  COMPUTE(1);

  // epilogue: L2 -> 5-kernel RBF sum, per-block reduction
  float bw = scal[0];
  float inv[5];
#pragma unroll
  for (int i = 0; i < 5; ++i) inv[i] = 1.0f / (bw * (float)(1 << i));

  float sum = 0.0f;
  int rbase = bi * 128 + arow0 + ((l >> 4) * 4);
  int cbase = bj * 128 + brow0 + l15;
#pragma unroll
  for (int m = 0; m < 4; ++m) {
    float4 sr = *(const float4*)(sq + rbase + m * 16);
    float sqr[4] = {sr.x, sr.y, sr.z, sr.w};
#pragma unroll
    for (int n = 0; n < 4; ++n) {
      float sc = sq[cbase + n * 16];
#pragma unroll
      for (int r = 0; r < 4; ++r) {
        float L2 = sqr[r] + sc - 2.0f * acc[m][n][r];
        L2 = fmaxf(L2, 0.0f);
#pragma unroll
        for (int i = 0; i < 5; ++i) {
          float s = fminf(L2 * inv[i], 50.0f);
          sum += __expf(-s);
        }
      }
    }
  }
  for (int o = 32; o; o >>= 1) sum += __shfl_xor(sum, o);

  __syncthreads();                 // all LDS reads done; reuse As as scratch
  float* red = (float*)&As[0][0];
  if (l == 0) red[w] = sum;
  __syncthreads();
  if (tid == 0) {
    double tot = (double)red[0] + red[1] + red[2] + red[3];
    int cat = (bi >= 16) * 2 + (bj >= 16);
    atomicAdd(accd + cat, tot);
    if (bi != bj) {
      int catT = (bj >= 16) * 2 + (bi >= 16);
      atomicAdd(accd + catT, tot);
    }
  }
}

__global__ void k_final(const double* __restrict__ accd,
                        const float* __restrict__ scal,
                        float* __restrict__ out) {
  double loss = (accd[0] + accd[3] - accd[1] - accd[2]) * (1.0 / 4194304.0);
  if (!isfinite(loss)) loss = (double)scal[1];
  out[0] = (float)loss;
}

extern "C" void kernel_launch(void* const* d_in, const int* in_sizes, int n_in,
                              void* d_out, int out_size, void* d_ws, size_t ws_size,
                              hipStream_t stream) {
  const float* src = (const float*)d_in[0];
  const float* tgt = (const float*)d_in[1];
  char* ws = (char*)d_ws;
  __bf16* Tb     = (__bf16*)(ws + TB_OFF);
  float*  sq     = (float*)(ws + SQ_OFF);
  float*  cs_src = (float*)(ws + CS_SRC_OFF);
  float*  cs_tgt = (float*)(ws + CS_TGT_OFF);
  double* accd   = (double*)(ws + ACC_OFF);
  float*  scal   = (float*)(ws + SCAL_OFF);

  // zero colsums + category accumulators (ws is NOT re-poisoned between replays)
  hipMemsetAsync(ws + CS_SRC_OFF, 0, (DD * 4) * 2 + 4 * 8, stream);

  k_prep<<<256, 256, 0, stream>>>(src, tgt, Tb, sq, cs_src, cs_tgt);
  k_bw<<<1, 1024, 0, stream>>>(sq, cs_src, cs_tgt, scal);
  k_mmd<<<NTRI, 256, 0, stream>>>(Tb, sq, scal, accd);
  k_final<<<1, 1, 0, stream>>>(accd, scal, (float*)d_out);
}

// Round 4
// 122.888 us; speedup vs baseline: 1.5975x; 1.1791x over previous
//
#include <hip/hip_runtime.h>
#include <cstdint>
#include <cmath>

#define DD 2048
#define NROW 4096
#define BHALF 2048
#define NT 64              // K-tiles of 32

typedef __attribute__((ext_vector_type(8))) __bf16 bf16x8;
typedef __attribute__((ext_vector_type(4))) float f32x4;

typedef __attribute__((address_space(1))) const void* as1cv;
typedef __attribute__((address_space(3))) void* as3v;

__device__ __forceinline__ void gload_lds16(const void* g, void* l) {
  __builtin_amdgcn_global_load_lds((as1cv)g, (as3v)l, 16, 0, 0);
}

__device__ __forceinline__ float fixv(float x) {
  if (isnan(x)) return 0.0f;
  if (isinf(x)) return x > 0.0f ? 10000.0f : -10000.0f;
  return x;
}

// ---- workspace layout (bytes) ----
constexpr size_t TB_OFF     = 0;                              // bf16 total [4096][2048]
constexpr size_t SQ_OFF     = (size_t)NROW * DD * 2;          // f32[4096]
constexpr size_t CS_SRC_OFF = SQ_OFF + NROW * 4;              // f32[2048]
constexpr size_t CS_TGT_OFF = CS_SRC_OFF + DD * 4;            // f32[2048]
constexpr size_t ACC_OFF    = CS_TGT_OFF + DD * 4;            // f64[4]
constexpr size_t SCAL_OFF   = ACC_OFF + 4 * 8;                // f32 lin

// Pass 1: nan_to_num, bf16 convert, row sum-of-squares, column sums.
// 256 blocks x 512 threads. Block = 16 rows; half 0 rows 0-7, half 1 rows 8-15.
__global__ __launch_bounds__(512) void k_prep(const float* __restrict__ src,
                                              const float* __restrict__ tgt,
                                              __bf16* __restrict__ Tb,
                                              float* __restrict__ sq,
                                              float* __restrict__ cs_src,
                                              float* __restrict__ cs_tgt) {
  int b = blockIdx.x;
  int t = threadIdx.x, l = t & 63, w = t >> 6;
  int half = t >> 8;             // 0: rows 0-7, 1: rows 8-15
  int tc = t & 255;              // col group (8 cols each)
  int row0 = b * 16;
  const float* base = (b < 128) ? (src + (size_t)row0 * DD)
                                : (tgt + (size_t)(row0 - BHALF) * DD);
  float* csp = (b < 128) ? cs_src : cs_tgt;
  int c0 = tc * 8;
  float cacc[8] = {0, 0, 0, 0, 0, 0, 0, 0};
  __shared__ float rbuf[8][8];
  __shared__ float cbuf[256][8];
#pragma unroll
  for (int r = 0; r < 8; ++r) {
    int row = half * 8 + r;
    const float4* p = (const float4*)(base + (size_t)row * DD + c0);
    float4 v0 = p[0], v1 = p[1];
    float x[8] = {v0.x, v0.y, v0.z, v0.w, v1.x, v1.y, v1.z, v1.w};
    bf16x8 bb;
    float a = 0.0f;
#pragma unroll
    for (int j = 0; j < 8; ++j) {
      float f = fixv(x[j]);
      a += f * f;
      cacc[j] += f;
      bb[j] = (__bf16)f;
    }
    *(bf16x8*)(Tb + (size_t)(row0 + row) * DD + c0) = bb;
    for (int o = 32; o; o >>= 1) a += __shfl_xor(a, o);
    if (l == 0) rbuf[w][r] = a;
  }
  if (half == 1) {
#pragma unroll
    for (int j = 0; j < 8; ++j) cbuf[tc][j] = cacc[j];
  }
  __syncthreads();
  if (half == 0) {
#pragma unroll
    for (int j = 0; j < 8; ++j) atomicAdd(&csp[c0 + j], cacc[j] + cbuf[tc][j]);
  }
  if (t < 16) {
    int h = t >> 3, rr = t & 7;
    sq[row0 + h * 8 + rr] = rbuf[h * 4 + 0][rr] + rbuf[h * 4 + 1][rr] +
                            rbuf[h * 4 + 2][rr] + rbuf[h * 4 + 3][rr];
  }
}

// Main: 256x256 tile, 8 waves (2M x 4N), BK=32, phase-split pipeline with
// raw s_barrier + counted vmcnt (loads stay in flight across barriers).
// Full 16x16 grid: all 256 CUs get exactly 1 block.
__global__ __launch_bounds__(512, 2) void k_mmd(const __bf16* __restrict__ Tb,
                                                const float* __restrict__ sq,
                                                const float* __restrict__ cs_src,
                                                const float* __restrict__ cs_tgt,
                                                double* __restrict__ accd,
                                                float* __restrict__ scal) {
  // XCD-chunked bijective swizzle (256 % 8 == 0)
  int lin = blockIdx.x;
  int t5 = (lin & 7) * 32 + (lin >> 3);
  int bi = t5 >> 4, bj = t5 & 15;

  // LDS: 2 bufs x 4 halves x (128 rows x 32 cols bf16 = 8KB) = 64 KiB
  __shared__ __attribute__((aligned(16))) __bf16 Sb[32768];

  int tid = threadIdx.x, l = tid & 63, w = tid >> 6;
  int wr = w >> 2, wc = w & 3;      // wave -> 128x64 output sub-tile
  int l15 = l & 15;

  f32x4 acc[8][4];
#pragma unroll
  for (int m = 0; m < 8; ++m)
#pragma unroll
    for (int n = 0; n < 4; ++n) acc[m][n] = (f32x4){0.0f, 0.0f, 0.0f, 0.0f};

  // ---- staging setup: 4 gload_lds calls per K-tile (A0,A1,B0,B1 halves) ----
  // call h: wave w writes rows w*16..w*16+15 of the half; lane l -> row w*16+(l>>2),
  // phys slot (l&3); global col pre-swizzled by involution slot^((row>>1)&3).
  int goff[4];
  int dstoff[4];
#pragma unroll
  for (int h = 0; h < 4; ++h) {
    int rowbase = ((h < 2) ? bi : bj) * 256 + (h & 1) * 128;
    goff[h] = (rowbase + w * 16 + (l >> 2)) * DD + (((l & 3) ^ ((l >> 3) & 3)) * 8);
    dstoff[h] = h * 4096 + w * 512;   // elems within one buffer
  }

  auto STAGE = [&](int sel, int tt) {
#pragma unroll
    for (int h = 0; h < 4; ++h)
      gload_lds16(Tb + goff[h] + tt * 32, (void*)(Sb + sel * 16384 + dstoff[h]));
  };

  // ---- LDS read addressing (swizzled): xk = (slot ^ ((row>>1)&3))*8 ----
  int xk = (((l >> 4) ^ ((l15 >> 1) & 3))) * 8;
  int aBase = wr * 4096 + l15 * 32 + xk;              // + m*512 + buf
  int bBase = (2 + (wc >> 1)) * 4096 + ((wc & 1) * 64 + l15) * 32 + xk;  // + n*512 + buf

  // ---- prologue: fill both buffers, wait only for tile 0 ----
  STAGE(0, 0);
  STAGE(1, 1);
  asm volatile("s_waitcnt vmcnt(4)" ::: "memory");
  __builtin_amdgcn_sched_barrier(0);
  __builtin_amdgcn_s_barrier();
  __builtin_amdgcn_sched_barrier(0);

#pragma unroll 1
  for (int t = 0; t < NT; ++t) {
    const int cur = t & 1;
    const int lb = cur * 16384;
    bf16x8 bF[4];
#pragma unroll
    for (int p = 0; p < 2; ++p) {
      bf16x8 aF[4];
      if (p == 0) {
#pragma unroll
        for (int n = 0; n < 4; ++n)
          bF[n] = *(const bf16x8*)(Sb + lb + bBase + n * 512);
      }
#pragma unroll
      for (int mm = 0; mm < 4; ++mm)
        aF[mm] = *(const bf16x8*)(Sb + lb + aBase + (p * 4 + mm) * 512);
      __builtin_amdgcn_s_barrier();
      asm volatile("s_waitcnt lgkmcnt(0)" ::: "memory");
      __builtin_amdgcn_sched_barrier(0);
      __builtin_amdgcn_s_setprio(1);
#pragma unroll
      for (int mm = 0; mm < 4; ++mm)
#pragma unroll
        for (int n = 0; n < 4; ++n)
          acc[p * 4 + mm][n] =
              __builtin_amdgcn_mfma_f32_16x16x32_bf16(aF[mm], bF[n], acc[p * 4 + mm][n], 0, 0, 0);
      __builtin_amdgcn_s_setprio(0);
      __builtin_amdgcn_s_barrier();
    }
    // ---- tile boundary: stage t+2 into the buffer just freed; counted wait ----
    __builtin_amdgcn_sched_barrier(0);
    if (t < NT - 2) {
      STAGE(cur, t + 2);
      asm volatile("s_waitcnt vmcnt(4)" ::: "memory");
    } else if (t == NT - 2) {
      asm volatile("s_waitcnt vmcnt(0)" ::: "memory");
    }
    __builtin_amdgcn_sched_barrier(0);
    __builtin_amdgcn_s_barrier();
    __builtin_amdgcn_sched_barrier(0);
  }

  // ---- in-block bandwidth (identical deterministic result in every block) ----
  float* red = (float*)Sb;
  float bw;
  {
    float ssq = 0.0f, s2 = 0.0f, dl = 0.0f;
#pragma unroll
    for (int k2 = 0; k2 < 8; ++k2) ssq += sq[tid + k2 * 512];
#pragma unroll
    for (int k2 = 0; k2 < 4; ++k2) {
      int c = tid + k2 * 512;
      float a = cs_src[c], b2 = cs_tgt[c];
      float s = a + b2;
      s2 += s * s;
      float d = (a - b2) * (1.0f / BHALF);
      dl += d * d;
    }
    for (int o = 32; o; o >>= 1) {
      ssq += __shfl_xor(ssq, o);
      s2  += __shfl_xor(s2, o);
      dl  += __shfl_xor(dl, o);
    }
    if (l == 0) { red[w] = ssq; red[8 + w] = s2; red[16 + w] = dl; }
    __syncthreads();
    double S = 0.0, Q = 0.0;
#pragma unroll
    for (int i = 0; i < 8; ++i) { S += red[i]; Q += red[8 + i]; }
    double meanL2 = 2.0 * S / (double)NROW - 2.0 * Q / ((double)NROW * (double)NROW);
    bw = (float)fmax(meanL2, 1e-6);
    if (tid == 0 && lin == 0) {
      double L = 0.0;
      for (int i = 0; i < 8; ++i) L += red[16 + i];
      scal[0] = (float)L;
    }
  }

  // ---- epilogue: L2 -> 5-kernel RBF sum ----
  float inv[5];
#pragma unroll
  for (int i = 0; i < 5; ++i) inv[i] = 1.0f / fmaxf(bw * (float)(1 << i), 1e-6f);

  float sum = 0.0f;
  int rbase = bi * 256 + wr * 128 + ((l >> 4) * 4);
  int cbase = bj * 256 + wc * 64 + l15;
#pragma unroll
  for (int m = 0; m < 8; ++m) {
    float4 sr = *(const float4*)(sq + rbase + m * 16);
    float sqr[4] = {sr.x, sr.y, sr.z, sr.w};
#pragma unroll
    for (int n = 0; n < 4; ++n) {
      float sc = sq[cbase + n * 16];
#pragma unroll
      for (int r = 0; r < 4; ++r) {
        float L2 = sqr[r] + sc - 2.0f * acc[m][n][r];
        L2 = fmaxf(L2, 0.0f);
#pragma unroll
        for (int i = 0; i < 5; ++i) {
          float s = fminf(L2 * inv[i], 50.0f);
          sum += __expf(-s);
        }
      }
    }
  }
  for (int o = 32; o; o >>= 1) sum += __shfl_xor(sum, o);
  if (l == 0) red[32 + w] = sum;
  __syncthreads();
  if (tid == 0) {
    double tot = 0.0;
    for (int i = 0; i < 8; ++i) tot += red[32 + i];
    int cat = (bi >= 8) * 2 + (bj >= 8);
    atomicAdd(accd + cat, tot);
  }
}

__global__ void k_final(const double* __restrict__ accd,
                        const float* __restrict__ scal,
                        float* __restrict__ out) {
  double loss = (accd[0] + accd[3] - accd[1] - accd[2]) * (1.0 / 4194304.0);
  if (!isfinite(loss)) loss = (double)scal[0];
  out[0] = (float)loss;
}

extern "C" void kernel_launch(void* const* d_in, const int* in_sizes, int n_in,
                              void* d_out, int out_size, void* d_ws, size_t ws_size,
                              hipStream_t stream) {
  const float* src = (const float*)d_in[0];
  const float* tgt = (const float*)d_in[1];
  char* ws = (char*)d_ws;
  __bf16* Tb     = (__bf16*)(ws + TB_OFF);
  float*  sq     = (float*)(ws + SQ_OFF);
  float*  cs_src = (float*)(ws + CS_SRC_OFF);
  float*  cs_tgt = (float*)(ws + CS_TGT_OFF);
  double* accd   = (double*)(ws + ACC_OFF);
  float*  scal   = (float*)(ws + SCAL_OFF);

  // zero colsums + category accumulators (ws is NOT re-poisoned between replays)
  hipMemsetAsync(ws + CS_SRC_OFF, 0, (DD * 4) * 2 + 4 * 8, stream);

  k_prep<<<256, 512, 0, stream>>>(src, tgt, Tb, sq, cs_src, cs_tgt);
  k_mmd<<<256, 512, 0, stream>>>(Tb, sq, cs_src, cs_tgt, accd, scal);
  k_final<<<1, 1, 0, stream>>>(accd, scal, (float*)d_out);
}

// Round 8
// 119.942 us; speedup vs baseline: 1.6368x; 1.0246x over previous
//
#include <hip/hip_runtime.h>
#include <cstdint>
#include <cmath>

#define DD 2048
#define NROW 4096
#define BHALF 2048
#define NT 64              // K-tiles of 32

typedef __attribute__((ext_vector_type(8))) __bf16 bf16x8;
typedef __attribute__((ext_vector_type(4))) float f32x4;

typedef __attribute__((address_space(1))) const void* as1cv;
typedef __attribute__((address_space(3))) void* as3v;

__device__ __forceinline__ void gload_lds16(const void* g, void* l) {
  __builtin_amdgcn_global_load_lds((as1cv)g, (as3v)l, 16, 0, 0);
}

__device__ __forceinline__ float fixv(float x) {
  if (isnan(x)) return 0.0f;
  if (isinf(x)) return x > 0.0f ? 10000.0f : -10000.0f;
  return x;
}

// ---- workspace layout (bytes) ----
constexpr size_t TB_OFF     = 0;                              // bf16 total [4096][2048]
constexpr size_t SQ_OFF     = (size_t)NROW * DD * 2;          // f32[4096]
constexpr size_t CS_SRC_OFF = SQ_OFF + NROW * 4;              // f32[2048]
constexpr size_t CS_TGT_OFF = CS_SRC_OFF + DD * 4;            // f32[2048]
constexpr size_t ACC_OFF    = CS_TGT_OFF + DD * 4;            // f64[4]
constexpr size_t SCAL_OFF   = ACC_OFF + 4 * 8;                // f32 lin

// Pass 1: nan_to_num, bf16 convert, row sum-of-squares, column sums.
__global__ __launch_bounds__(512) void k_prep(const float* __restrict__ src,
                                              const float* __restrict__ tgt,
                                              __bf16* __restrict__ Tb,
                                              float* __restrict__ sq,
                                              float* __restrict__ cs_src,
                                              float* __restrict__ cs_tgt) {
  int b = blockIdx.x;
  int t = threadIdx.x, l = t & 63, w = t >> 6;
  int half = t >> 8;             // 0: rows 0-7, 1: rows 8-15
  int tc = t & 255;              // col group (8 cols each)
  int row0 = b * 16;
  const float* base = (b < 128) ? (src + (size_t)row0 * DD)
                                : (tgt + (size_t)(row0 - BHALF) * DD);
  float* csp = (b < 128) ? cs_src : cs_tgt;
  int c0 = tc * 8;
  float cacc[8] = {0, 0, 0, 0, 0, 0, 0, 0};
  __shared__ float rbuf[8][8];
  __shared__ float cbuf[256][8];
#pragma unroll
  for (int r = 0; r < 8; ++r) {
    int row = half * 8 + r;
    const float4* p = (const float4*)(base + (size_t)row * DD + c0);
    float4 v0 = p[0], v1 = p[1];
    float x[8] = {v0.x, v0.y, v0.z, v0.w, v1.x, v1.y, v1.z, v1.w};
    bf16x8 bb;
    float a = 0.0f;
#pragma unroll
    for (int j = 0; j < 8; ++j) {
      float f = fixv(x[j]);
      a += f * f;
      cacc[j] += f;
      bb[j] = (__bf16)f;
    }
    *(bf16x8*)(Tb + (size_t)(row0 + row) * DD + c0) = bb;
    for (int o = 32; o; o >>= 1) a += __shfl_xor(a, o);
    if (l == 0) rbuf[w][r] = a;
  }
  if (half == 1) {
#pragma unroll
    for (int j = 0; j < 8; ++j) cbuf[tc][j] = cacc[j];
  }
  __syncthreads();
  if (half == 0) {
#pragma unroll
    for (int j = 0; j < 8; ++j) atomicAdd(&csp[c0 + j], cacc[j] + cbuf[tc][j]);
  }
  if (t < 16) {
    int h = t >> 3, rr = t & 7;
    sq[row0 + h * 8 + rr] = rbuf[h * 4 + 0][rr] + rbuf[h * 4 + 1][rr] +
                            rbuf[h * 4 + 2][rr] + rbuf[h * 4 + 3][rr];
  }
}

// Main: 256x256 tile, 8 waves (2M x 4N), BK=32, 3-buffer rotation.
// Tile t lives in buf t%3; tile t+2 staged into buf (t+2)%3, which holds the
// fully-consumed tile t-1 -> staging NEVER touches a buffer under read.
// Per tile: P0 {aF mh0 + bF all + stage A(t+2) | BAR | 16 MFMA | BAR},
//           P1 {aF mh1 + stage B(t+2) + vmcnt(4) | BAR | 16 MFMA | BAR}.
// vmcnt(4) at tP1: outstanding {A(t+1),B(t+1),A(t+2),B(t+2)}=8 -> oldest 4
// (tile t+1) complete, >=2 barriers before its first read at (t+1)P0.
__global__ __launch_bounds__(512, 2) void k_mmd(const __bf16* __restrict__ Tb,
                                                const float* __restrict__ sq,
                                                const float* __restrict__ cs_src,
                                                const float* __restrict__ cs_tgt,
                                                double* __restrict__ accd,
                                                float* __restrict__ scal) {
  // XCD-chunked bijective swizzle (256 % 8 == 0)
  int lin = blockIdx.x;
  int t5 = (lin & 7) * 32 + (lin >> 3);
  int bi = t5 >> 4, bj = t5 & 15;

  // LDS: 3 bufs x (A 256x32 + B 256x32) bf16 = 96 KiB
  __shared__ __attribute__((aligned(16))) __bf16 Sb[49152];

  int tid = threadIdx.x, l = tid & 63, w = tid >> 6;
  int wr = w >> 2, wc = w & 3;      // wave -> 128x64 output sub-tile
  int l15 = l & 15;

  f32x4 acc[8][4];
#pragma unroll
  for (int m = 0; m < 8; ++m)
#pragma unroll
    for (int n = 0; n < 4; ++n) acc[m][n] = (f32x4){0.0f, 0.0f, 0.0f, 0.0f};

  // ---- staging geometry (round-4 proven): one call = this wave's 16 rows of a
  // 128-row half; lane l -> row w*16+(l>>2), phys slot l&3; source col
  // pre-swizzled by involution slot^((row>>1)&3) = slot^((l>>3)&3).
  int colsw = ((l & 3) ^ ((l >> 3) & 3)) * 8;
  size_t gA0 = (size_t)(bi * 256 + w * 16 + (l >> 2)) * DD + colsw;
  size_t gB0 = (size_t)(bj * 256 + w * 16 + (l >> 2)) * DD + colsw;
  int dW = w * 512;                 // wave's LDS chunk within a 128-row half

#define CALLA(bf, h, T) gload_lds16(Tb + gA0 + (size_t)(h) * 128 * DD + (size_t)(T) * 32, \
                                    (void*)(Sb + (bf) + (h) * 4096 + dW))
#define CALLB(bf, h, T) gload_lds16(Tb + gB0 + (size_t)(h) * 128 * DD + (size_t)(T) * 32, \
                                    (void*)(Sb + (bf) + 8192 + (h) * 4096 + dW))

  // ---- LDS read addressing (round-4 proven): xk = (slot ^ ((row>>1)&3))*8 ----
  int xk = (((l >> 4) ^ ((l15 >> 1) & 3))) * 8;
  int aB = (wr * 128 + l15) * 32 + xk;              // + buf + m*512
  int bB = 8192 + (wc * 64 + l15) * 32 + xk;        // + buf + n*512

#define BAR()  __builtin_amdgcn_s_barrier()
#define SBAR() __builtin_amdgcn_sched_barrier(0)
#define LGKM0() asm volatile("s_waitcnt lgkmcnt(0)" ::: "memory")

  // ---- prologue: stage tile0 -> buf0, tile1 -> buf1; wait tile0 ----
  CALLA(0, 0, 0); CALLA(0, 1, 0); CALLB(0, 0, 0); CALLB(0, 1, 0);
  CALLA(16384, 0, 1); CALLA(16384, 1, 1); CALLB(16384, 0, 1); CALLB(16384, 1, 1);
  asm volatile("s_waitcnt vmcnt(4)" ::: "memory");
  SBAR(); BAR(); SBAR();

  int selO = 0, stgO = 32768;   // element offsets of buf t%3 and buf (t+2)%3
#pragma unroll 1
  for (int t = 0; t < NT; ++t) {
    // ---------------- P0: m-half 0, all B; stage A(t+2) ----------------
    bf16x8 aF[4], bF[4];
#pragma unroll
    for (int m = 0; m < 4; ++m)
      aF[m] = *(const bf16x8*)(Sb + selO + aB + m * 512);
#pragma unroll
    for (int n = 0; n < 4; ++n)
      bF[n] = *(const bf16x8*)(Sb + selO + bB + n * 512);
    if (t < NT - 2) { CALLA(stgO, 0, t + 2); CALLA(stgO, 1, t + 2); }
    SBAR(); BAR();
    LGKM0(); SBAR();
    __builtin_amdgcn_s_setprio(1);
#pragma unroll
    for (int m = 0; m < 4; ++m)
#pragma unroll
      for (int n = 0; n < 4; ++n)
        acc[m][n] = __builtin_amdgcn_mfma_f32_16x16x32_bf16(aF[m], bF[n], acc[m][n], 0, 0, 0);
    __builtin_amdgcn_s_setprio(0);
    SBAR(); BAR();
    // ---------------- P1: m-half 1; stage B(t+2); counted wait ----------------
    bf16x8 aG[4];
#pragma unroll
    for (int m = 0; m < 4; ++m)
      aG[m] = *(const bf16x8*)(Sb + selO + aB + (4 + m) * 512);
    if (t < NT - 2) {
      CALLB(stgO, 0, t + 2); CALLB(stgO, 1, t + 2);
      asm volatile("s_waitcnt vmcnt(4)" ::: "memory");
    } else if (t == NT - 2) {
      asm volatile("s_waitcnt vmcnt(0)" ::: "memory");
    }
    SBAR(); BAR();
    LGKM0(); SBAR();
    __builtin_amdgcn_s_setprio(1);
#pragma unroll
    for (int m = 0; m < 4; ++m)
#pragma unroll
      for (int n = 0; n < 4; ++n)
        acc[4 + m][n] = __builtin_amdgcn_mfma_f32_16x16x32_bf16(aG[m], bF[n], acc[4 + m][n], 0, 0, 0);
    __builtin_amdgcn_s_setprio(0);
    SBAR(); BAR();
    // rotate buffers: sel -> +1 mod 3, stg -> +1 mod 3 (offsets in elements)
    selO = (selO == 32768) ? 0 : selO + 16384;
    stgO = (stgO == 32768) ? 0 : stgO + 16384;
  }

  // ---- in-block bandwidth (identical deterministic result in every block) ----
  float* red = (float*)Sb;
  float bw;
  {
    float ssq = 0.0f, s2 = 0.0f, dl = 0.0f;
#pragma unroll
    for (int k2 = 0; k2 < 8; ++k2) ssq += sq[tid + k2 * 512];
#pragma unroll
    for (int k2 = 0; k2 < 4; ++k2) {
      int c = tid + k2 * 512;
      float a = cs_src[c], b2 = cs_tgt[c];
      float s = a + b2;
      s2 += s * s;
      float d = (a - b2) * (1.0f / BHALF);
      dl += d * d;
    }
    for (int o = 32; o; o >>= 1) {
      ssq += __shfl_xor(ssq, o);
      s2  += __shfl_xor(s2, o);
      dl  += __shfl_xor(dl, o);
    }
    if (l == 0) { red[w] = ssq; red[8 + w] = s2; red[16 + w] = dl; }
    __syncthreads();
    double S = 0.0, Q = 0.0;
#pragma unroll
    for (int i = 0; i < 8; ++i) { S += red[i]; Q += red[8 + i]; }
    double meanL2 = 2.0 * S / (double)NROW - 2.0 * Q / ((double)NROW * (double)NROW);
    bw = (float)fmax(meanL2, 1e-6);
    if (tid == 0 && lin == 0) {
      double L = 0.0;
      for (int i = 0; i < 8; ++i) L += red[16 + i];
      scal[0] = (float)L;
    }
  }

  // ---- epilogue: L2 -> 5-kernel RBF sum ----
  float inv[5];
#pragma unroll
  for (int i = 0; i < 5; ++i) inv[i] = 1.0f / fmaxf(bw * (float)(1 << i), 1e-6f);

  float sum = 0.0f;
  int rbase = bi * 256 + wr * 128 + ((l >> 4) * 4);
  int cbase = bj * 256 + wc * 64 + l15;
#pragma unroll
  for (int m = 0; m < 8; ++m) {
    float4 sr = *(const float4*)(sq + rbase + m * 16);
    float sqr[4] = {sr.x, sr.y, sr.z, sr.w};
#pragma unroll
    for (int n = 0; n < 4; ++n) {
      float sc = sq[cbase + n * 16];
#pragma unroll
      for (int r = 0; r < 4; ++r) {
        float L2 = sqr[r] + sc - 2.0f * acc[m][n][r];
        L2 = fmaxf(L2, 0.0f);
#pragma unroll
        for (int i = 0; i < 5; ++i) {
          float s = fminf(L2 * inv[i], 50.0f);
          sum += __expf(-s);
        }
      }
    }
  }
  for (int o = 32; o; o >>= 1) sum += __shfl_xor(sum, o);
  if (l == 0) red[32 + w] = sum;
  __syncthreads();
  if (tid == 0) {
    double tot = 0.0;
    for (int i = 0; i < 8; ++i) tot += red[32 + i];
    int cat = (bi >= 8) * 2 + (bj >= 8);
    atomicAdd(accd + cat, tot);
  }
}

__global__ void k_final(const double* __restrict__ accd,
                        const float* __restrict__ scal,
                        float* __restrict__ out) {
  double loss = (accd[0] + accd[3] - accd[1] - accd[2]) * (1.0 / 4194304.0);
  if (!isfinite(loss)) loss = (double)scal[0];
  out[0] = (float)loss;
}

extern "C" void kernel_launch(void* const* d_in, const int* in_sizes, int n_in,
                              void* d_out, int out_size, void* d_ws, size_t ws_size,
                              hipStream_t stream) {
  const float* src = (const float*)d_in[0];
  const float* tgt = (const float*)d_in[1];
  char* ws = (char*)d_ws;
  __bf16* Tb     = (__bf16*)(ws + TB_OFF);
  float*  sq     = (float*)(ws + SQ_OFF);
  float*  cs_src = (float*)(ws + CS_SRC_OFF);
  float*  cs_tgt = (float*)(ws + CS_TGT_OFF);
  double* accd   = (double*)(ws + ACC_OFF);
  float*  scal   = (float*)(ws + SCAL_OFF);

  // zero colsums + category accumulators (ws is NOT re-poisoned between replays)
  hipMemsetAsync(ws + CS_SRC_OFF, 0, (DD * 4) * 2 + 4 * 8, stream);

  k_prep<<<256, 512, 0, stream>>>(src, tgt, Tb, sq, cs_src, cs_tgt);
  k_mmd<<<256, 512, 0, stream>>>(Tb, sq, cs_src, cs_tgt, accd, scal);
  k_final<<<1, 1, 0, stream>>>(accd, scal, (float*)d_out);
}